// Round 10
// baseline (324.418 us; speedup 1.0000x reference)
//
#include <hip/hip_runtime.h>

#define N_NODES 50000
#define N_EDGES 600000
#define F_IN 128
#define H1 64
#define H2 32
#define NBLK ((N_NODES + 255) / 256)        // 196 scan blocks
#define PREP_BLOCKS 41                      // 10336 weight elems / 256
#define CNT_BLOCKS ((N_EDGES / 4 + 255) / 256)   // 586
#define GEMM1_BLOCKS ((N_NODES + 63) / 64)  // 782
#define FILL_BLOCKS ((N_EDGES / 4 + 255) / 256)  // 586

// ---- bf16 pack/unpack helpers (round-to-nearest-even) ---------------------
__device__ inline unsigned bf_round(float x) {
  unsigned u = __float_as_uint(x);
  u += 0x7FFFu + ((u >> 16) & 1u);
  return u >> 16;
}
__device__ inline unsigned pack_bf2(float a, float b) {
  return (bf_round(b) << 16) | bf_round(a);
}
__device__ inline float2 unpack_bf2(unsigned u) {
  return make_float2(__uint_as_float(u << 16), __uint_as_float(u & 0xFFFF0000u));
}

// ---------------------------------------------------------------------------
// Kernel A: fold GIN MLP weights (blocks 0..40)  +  count edges (rest).
// ---------------------------------------------------------------------------
__global__ __launch_bounds__(256) void prep_and_count(
    const float* __restrict__ w1a, const float* __restrict__ b1a,
    const float* __restrict__ w1b, const float* __restrict__ b1b,
    const float* __restrict__ w2a, const float* __restrict__ b2a,
    const float* __restrict__ w2b, const float* __restrict__ b2b,
    float* __restrict__ M1, float* __restrict__ c1,
    float* __restrict__ M2, float* __restrict__ c2,
    const int* __restrict__ ei, int* __restrict__ counts) {
  if (blockIdx.x >= PREP_BLOCKS) {
    int t = (blockIdx.x - PREP_BLOCKS) * 256 + threadIdx.x;
    if (t < N_EDGES / 4) {
      int4 d4 = *reinterpret_cast<const int4*>(&ei[N_EDGES + t * 4]);
      atomicAdd(&counts[d4.x], 1);
      atomicAdd(&counts[d4.y], 1);
      atomicAdd(&counts[d4.z], 1);
      atomicAdd(&counts[d4.w], 1);
    }
    return;
  }
  int i = blockIdx.x * 256 + threadIdx.x;
  if (i < F_IN * H1) {
    int f = i >> 6, h = i & 63;
    float s = 0.f;
    for (int m = 0; m < H1; ++m) s += w1a[m * F_IN + f] * w1b[h * H1 + m];
    M1[i] = s;
    return;
  }
  i -= F_IN * H1;
  if (i < H1) {
    float s = b1b[i];
    for (int m = 0; m < H1; ++m) s += b1a[m] * w1b[i * H1 + m];
    c1[i] = s;
    return;
  }
  i -= H1;
  if (i < H1 * H2) {
    int h = i >> 5, o = i & 31;
    float s = 0.f;
    for (int m = 0; m < H2; ++m) s += w2a[m * H1 + h] * w2b[o * H2 + m];
    M2[i] = s;
    return;
  }
  i -= H1 * H2;
  if (i < H2) {
    float s = b2b[i];
    for (int m = 0; m < H2; ++m) s += b2a[m] * w2b[i * H2 + m];
    c2[i] = s;
  }
}

// -------------------- CSR scan phases --------------------------------------
__global__ __launch_bounds__(256) void block_sums(const int* __restrict__ counts,
                                                  int* __restrict__ bsums) {
  __shared__ int s[256];
  int t = threadIdx.x;
  int i = blockIdx.x * 256 + t;
  s[t] = (i < N_NODES) ? counts[i] : 0;
  __syncthreads();
  for (int off = 128; off > 0; off >>= 1) {
    if (t < off) s[t] += s[t + off];
    __syncthreads();
  }
  if (t == 0) bsums[blockIdx.x] = s[0];
}

// emit_rowptr with the bsums scan folded in: every block redundantly scans
// the NBLK (=196) block sums in LDS (trivial), then does its local scan.
__global__ __launch_bounds__(256) void emit_rowptr(const int* __restrict__ counts,
                                                   const int* __restrict__ bsums,
                                                   int* __restrict__ row_ptr,
                                                   int* __restrict__ cursor) {
  __shared__ int sb[256];
  __shared__ int s[256];
  int t = threadIdx.x;
  // scan of block sums (inclusive) in sb
  int bv = (t < NBLK) ? bsums[t] : 0;
  sb[t] = bv;
  __syncthreads();
  for (int off = 1; off < 256; off <<= 1) {
    int u = (t >= off) ? sb[t - off] : 0;
    __syncthreads();
    sb[t] += u;
    __syncthreads();
  }
  if (blockIdx.x == 0 && t == NBLK - 1) row_ptr[N_NODES] = sb[t];
  int boff = (blockIdx.x == 0) ? 0 : sb[blockIdx.x - 1];
  // local scan of counts
  int i = blockIdx.x * 256 + t;
  int v = (i < N_NODES) ? counts[i] : 0;
  s[t] = v;
  __syncthreads();
  for (int off = 1; off < 256; off <<= 1) {
    int u = (t >= off) ? s[t - off] : 0;
    __syncthreads();
    s[t] += u;
    __syncthreads();
  }
  if (i < N_NODES) {
    int ex = boff + s[t] - v;
    row_ptr[i] = ex;
    cursor[i] = ex;
  }
}

// ---------------------------------------------------------------------------
// Merged dispatch: blocks [0, GEMM1_BLOCKS) -> y = x@M1 -> bf16,
//                  blocks [GEMM1_BLOCKS, +FILL_BLOCKS) -> packed CSR fill.
// ---------------------------------------------------------------------------
__global__ __launch_bounds__(256) void gemm1_fill(
    const float* __restrict__ x, const float* __restrict__ M1,
    unsigned* __restrict__ ybf, const int* __restrict__ ei,
    const float* __restrict__ ea, int* __restrict__ cursor,
    int2* __restrict__ csr) {
  __shared__ float sW[F_IN * H1];   // 32 KiB, [k][col]
  __shared__ float sX[32][H1];      // 8 KiB,  [k][row]
  if (blockIdx.x >= GEMM1_BLOCKS) {
    int t = (blockIdx.x - GEMM1_BLOCKS) * 256 + threadIdx.x;
    if (t < N_EDGES / 4) {
      int4 s4 = *reinterpret_cast<const int4*>(&ei[4 * t]);
      int4 d4 = *reinterpret_cast<const int4*>(&ei[N_EDGES + 4 * t]);
      float4 w4 = *reinterpret_cast<const float4*>(&ea[4 * t]);
      int p0 = atomicAdd(&cursor[d4.x], 1);
      csr[p0] = make_int2(s4.x, __float_as_int(w4.x));
      int p1 = atomicAdd(&cursor[d4.y], 1);
      csr[p1] = make_int2(s4.y, __float_as_int(w4.y));
      int p2 = atomicAdd(&cursor[d4.z], 1);
      csr[p2] = make_int2(s4.z, __float_as_int(w4.z));
      int p3 = atomicAdd(&cursor[d4.w], 1);
      csr[p3] = make_int2(s4.w, __float_as_int(w4.w));
    }
    return;
  }
  int tid = threadIdx.x;
  for (int i = tid; i < F_IN * H1; i += 256) sW[i] = M1[i];

  int row0 = blockIdx.x * 64;
  int tr = tid >> 4;   // 0..15
  int tc = tid & 15;   // 0..15
  int lrow = tid & 63;
  int kgrp = tid >> 6; // 0..3
  const float* xrow = x + (long long)(row0 + lrow) * F_IN;
  bool rvalid = (row0 + lrow) < N_NODES;

  float acc[4][4] = {{0.f}};

  for (int kc = 0; kc < 4; ++kc) {
    float4 v0 = make_float4(0.f, 0.f, 0.f, 0.f);
    float4 v1 = make_float4(0.f, 0.f, 0.f, 0.f);
    if (rvalid) {
      v0 = *reinterpret_cast<const float4*>(xrow + kc * 32 + kgrp * 8);
      v1 = *reinterpret_cast<const float4*>(xrow + kc * 32 + kgrp * 8 + 4);
    }
    __syncthreads();
    sX[kgrp * 8 + 0][lrow] = v0.x;
    sX[kgrp * 8 + 1][lrow] = v0.y;
    sX[kgrp * 8 + 2][lrow] = v0.z;
    sX[kgrp * 8 + 3][lrow] = v0.w;
    sX[kgrp * 8 + 4][lrow] = v1.x;
    sX[kgrp * 8 + 5][lrow] = v1.y;
    sX[kgrp * 8 + 6][lrow] = v1.z;
    sX[kgrp * 8 + 7][lrow] = v1.w;
    __syncthreads();
#pragma unroll
    for (int k = 0; k < 32; ++k) {
      float4 a = *reinterpret_cast<const float4*>(&sX[k][tr * 4]);
      float4 b = *reinterpret_cast<const float4*>(&sW[(kc * 32 + k) * H1 + tc * 4]);
      acc[0][0] += a.x * b.x; acc[0][1] += a.x * b.y;
      acc[0][2] += a.x * b.z; acc[0][3] += a.x * b.w;
      acc[1][0] += a.y * b.x; acc[1][1] += a.y * b.y;
      acc[1][2] += a.y * b.z; acc[1][3] += a.y * b.w;
      acc[2][0] += a.z * b.x; acc[2][1] += a.z * b.y;
      acc[2][2] += a.z * b.z; acc[2][3] += a.z * b.w;
      acc[3][0] += a.w * b.x; acc[3][1] += a.w * b.y;
      acc[3][2] += a.w * b.z; acc[3][3] += a.w * b.w;
    }
  }
#pragma unroll
  for (int i = 0; i < 4; ++i) {
    int row = row0 + tr * 4 + i;
    if (row < N_NODES) {
      uint2 o;
      o.x = pack_bf2(acc[i][0], acc[i][1]);
      o.y = pack_bf2(acc[i][2], acc[i][3]);
      *reinterpret_cast<uint2*>(&ybf[(unsigned)row * 32 + tc * 2]) = o;
    }
  }
}

// ---------------------------------------------------------------------------
// gin2 (fused, LEAN): per 64-node tile:
//   phase 1: wave per node (halves split edge list, 4-unrolled), compute
//            h = relu((1+e1)*y_self + sum y_nb + c1) -> LDS sh[k][node]
//            (row stride 68 keeps rows 16B-aligned, MLP reads conflict-free)
//   phase 2: register-tiled MLP z = h @ M2 -> packed bf16 (gemm2 body).
// Keeps the gather body at agg_h's register footprint (R7 lesson: gather
// kernels must stay VGPR-lean; 196-VGPR fusion collapsed occupancy).
// ---------------------------------------------------------------------------
__global__ __launch_bounds__(256) void gin2(
    const unsigned* __restrict__ ybf, const int* __restrict__ row_ptr,
    const int2* __restrict__ csr, const float* __restrict__ M2,
    const float* __restrict__ c1, const float* __restrict__ eps1p,
    unsigned* __restrict__ zbf) {
  __shared__ float sW[H1 * H2];   // 8 KiB  [k][o]
  __shared__ float sh[H1][68];    // 17 KiB [k][node], padded
  int tid = threadIdx.x;
  for (int i = tid; i < H1 * H2; i += 256) sW[i] = M2[i];

  int row0 = blockIdx.x * 64;
  int wave = tid >> 6;   // 0..3
  int lane = tid & 63;
  int half = lane >> 5;
  int j = lane & 31;
  float eps1 = 1.0f + *eps1p;
  float2 c = *reinterpret_cast<const float2*>(&c1[2 * j]);

  for (int rnd = 0; rnd < 16; ++rnd) {
    int nl = rnd * 4 + wave;
    int node = row0 + nl;
    float a0 = 0.f, a1 = 0.f;
    if (node < N_NODES) {
      int start = row_ptr[node], end = row_ptr[node + 1];
      int mid = start + ((end - start + 1) >> 1);
      int b0 = half ? mid : start;
      int b1 = half ? end : mid;
      int e = b0;
      for (; e + 4 <= b1; e += 4) {
        int s0 = csr[e + 0].x;
        int s1 = csr[e + 1].x;
        int s2 = csr[e + 2].x;
        int s3 = csr[e + 3].x;
        float2 u0 = unpack_bf2(ybf[(unsigned)s0 * 32 + j]);
        float2 u1 = unpack_bf2(ybf[(unsigned)s1 * 32 + j]);
        float2 u2 = unpack_bf2(ybf[(unsigned)s2 * 32 + j]);
        float2 u3 = unpack_bf2(ybf[(unsigned)s3 * 32 + j]);
        a0 += (u0.x + u1.x) + (u2.x + u3.x);
        a1 += (u0.y + u1.y) + (u2.y + u3.y);
      }
      float2 t0 = make_float2(0.f, 0.f), t1 = make_float2(0.f, 0.f),
             t2 = make_float2(0.f, 0.f);
      if (e + 0 < b1) t0 = unpack_bf2(ybf[(unsigned)csr[e + 0].x * 32 + j]);
      if (e + 1 < b1) t1 = unpack_bf2(ybf[(unsigned)csr[e + 1].x * 32 + j]);
      if (e + 2 < b1) t2 = unpack_bf2(ybf[(unsigned)csr[e + 2].x * 32 + j]);
      a0 += (t0.x + t1.x) + t2.x;
      a1 += (t0.y + t1.y) + t2.y;
    }
    a0 += __shfl_xor(a0, 32);
    a1 += __shfl_xor(a1, 32);
    if (half == 0) {
      float h0 = 0.f, h1 = 0.f;
      if (node < N_NODES) {
        float2 self = unpack_bf2(ybf[(unsigned)node * 32 + j]);
        h0 = fmaxf(eps1 * self.x + a0 + c.x, 0.f);
        h1 = fmaxf(eps1 * self.y + a1 + c.y, 0.f);
      }
      sh[2 * j][nl] = h0;
      sh[2 * j + 1][nl] = h1;
    }
  }
  __syncthreads();

  // phase 2: z = h @ M2 (4 rows x 2 cols per thread)
  int tr = tid >> 4;  // 0..15
  int tc = tid & 15;  // 0..15
  float acc[4][2] = {{0.f}};
#pragma unroll
  for (int k = 0; k < H1; ++k) {
    float4 a = *reinterpret_cast<const float4*>(&sh[k][tr * 4]);
    float2 b = *reinterpret_cast<const float2*>(&sW[k * H2 + tc * 2]);
    acc[0][0] += a.x * b.x; acc[0][1] += a.x * b.y;
    acc[1][0] += a.y * b.x; acc[1][1] += a.y * b.y;
    acc[2][0] += a.z * b.x; acc[2][1] += a.z * b.y;
    acc[3][0] += a.w * b.x; acc[3][1] += a.w * b.y;
  }
#pragma unroll
  for (int i = 0; i < 4; ++i) {
    int row = row0 + tr * 4 + i;
    if (row < N_NODES)
      zbf[(unsigned)row * 16 + tc] = pack_bf2(acc[i][0], acc[i][1]);
  }
}

// ---- gin3: h2 = relu((1+e2)*z_self + sum z_nb + c2); p=h2.wl, r=h2.wr -----
// 16 lanes per node (lane j = features 2j,2j+1); 16 nodes / block.
__global__ __launch_bounds__(256) void gin3(
    const unsigned* __restrict__ zbf, const int* __restrict__ row_ptr,
    const int2* __restrict__ csr, const float* __restrict__ c2,
    const float* __restrict__ eps2p, const float* __restrict__ wl,
    const float* __restrict__ wr, float* __restrict__ p,
    float* __restrict__ r) {
  int tid = blockIdx.x * 256 + threadIdx.x;
  int node = tid >> 4;
  if (node >= N_NODES) return;
  int j = tid & 15;
  int start = row_ptr[node], end = row_ptr[node + 1];
  float a0 = 0.f, a1 = 0.f;
  int e = start;
  for (; e + 8 <= end; e += 8) {
    int s0 = csr[e + 0].x; int s1 = csr[e + 1].x;
    int s2 = csr[e + 2].x; int s3 = csr[e + 3].x;
    int s4 = csr[e + 4].x; int s5 = csr[e + 5].x;
    int s6 = csr[e + 6].x; int s7 = csr[e + 7].x;
    float2 u0 = unpack_bf2(zbf[(unsigned)s0 * 16 + j]);
    float2 u1 = unpack_bf2(zbf[(unsigned)s1 * 16 + j]);
    float2 u2 = unpack_bf2(zbf[(unsigned)s2 * 16 + j]);
    float2 u3 = unpack_bf2(zbf[(unsigned)s3 * 16 + j]);
    float2 u4 = unpack_bf2(zbf[(unsigned)s4 * 16 + j]);
    float2 u5 = unpack_bf2(zbf[(unsigned)s5 * 16 + j]);
    float2 u6 = unpack_bf2(zbf[(unsigned)s6 * 16 + j]);
    float2 u7 = unpack_bf2(zbf[(unsigned)s7 * 16 + j]);
    a0 += ((u0.x + u1.x) + (u2.x + u3.x)) + ((u4.x + u5.x) + (u6.x + u7.x));
    a1 += ((u0.y + u1.y) + (u2.y + u3.y)) + ((u4.y + u5.y) + (u6.y + u7.y));
  }
  for (; e + 4 <= end; e += 4) {
    int s0 = csr[e + 0].x; int s1 = csr[e + 1].x;
    int s2 = csr[e + 2].x; int s3 = csr[e + 3].x;
    float2 u0 = unpack_bf2(zbf[(unsigned)s0 * 16 + j]);
    float2 u1 = unpack_bf2(zbf[(unsigned)s1 * 16 + j]);
    float2 u2 = unpack_bf2(zbf[(unsigned)s2 * 16 + j]);
    float2 u3 = unpack_bf2(zbf[(unsigned)s3 * 16 + j]);
    a0 += (u0.x + u1.x) + (u2.x + u3.x);
    a1 += (u0.y + u1.y) + (u2.y + u3.y);
  }
  float2 t0 = make_float2(0.f, 0.f), t1 = make_float2(0.f, 0.f),
         t2 = make_float2(0.f, 0.f);
  if (e + 0 < end) t0 = unpack_bf2(zbf[(unsigned)csr[e + 0].x * 16 + j]);
  if (e + 1 < end) t1 = unpack_bf2(zbf[(unsigned)csr[e + 1].x * 16 + j]);
  if (e + 2 < end) t2 = unpack_bf2(zbf[(unsigned)csr[e + 2].x * 16 + j]);
  a0 += (t0.x + t1.x) + t2.x;
  a1 += (t0.y + t1.y) + t2.y;
  float eps2 = 1.0f + *eps2p;
  float2 self = unpack_bf2(zbf[(unsigned)node * 16 + j]);
  float2 c = *reinterpret_cast<const float2*>(&c2[2 * j]);
  float h0 = fmaxf(eps2 * self.x + a0 + c.x, 0.f);
  float h1 = fmaxf(eps2 * self.y + a1 + c.y, 0.f);
  float2 l = *reinterpret_cast<const float2*>(&wl[2 * j]);
  float2 w = *reinterpret_cast<const float2*>(&wr[2 * j]);
  float pd = h0 * l.x + h1 * l.y;
  float rd = h0 * w.x + h1 * w.y;
#pragma unroll
  for (int m = 8; m >= 1; m >>= 1) {
    pd += __shfl_xor(pd, m, 16);
    rd += __shfl_xor(rd, m, 16);
  }
  if (j == 0) {
    p[node] = pd;
    r[node] = rd;
  }
}

// ---- SAGE: mean of ew*p[src] over in-edges + root path, relu --------------
__global__ __launch_bounds__(256) void sage_out(
    const int* __restrict__ row_ptr, const int2* __restrict__ csr,
    const float* __restrict__ p, const float* __restrict__ r,
    const float* __restrict__ blp, float* __restrict__ out) {
  int idx = blockIdx.x * 256 + threadIdx.x;
  int node = idx >> 4;
  if (node >= N_NODES) return;
  int l = idx & 15;
  int start = row_ptr[node], end = row_ptr[node + 1];
  float acc = 0.f;
  for (int e = start + l; e < end; e += 16) {
    int2 c = csr[e];
    acc += __int_as_float(c.y) * p[c.x];
  }
#pragma unroll
  for (int m = 8; m >= 1; m >>= 1) acc += __shfl_xor(acc, m, 16);
  if (l == 0) {
    float mean = acc / fmaxf((float)(end - start), 1.0f);
    out[node] = fmaxf(mean + blp[0] + r[node], 0.f);
  }
}

extern "C" void kernel_launch(void* const* d_in, const int* in_sizes, int n_in,
                              void* d_out, int out_size, void* d_ws,
                              size_t ws_size, hipStream_t stream) {
  const float* x = (const float*)d_in[0];
  const int* ei = (const int*)d_in[1];
  const float* ea = (const float*)d_in[2];
  const float* w1a = (const float*)d_in[3];
  const float* b1a = (const float*)d_in[4];
  const float* w1b = (const float*)d_in[5];
  const float* b1b = (const float*)d_in[6];
  const float* eps1 = (const float*)d_in[7];
  const float* w2a = (const float*)d_in[8];
  const float* b2a = (const float*)d_in[9];
  const float* w2b = (const float*)d_in[10];
  const float* b2b = (const float*)d_in[11];
  const float* eps2 = (const float*)d_in[12];
  const float* wl = (const float*)d_in[13];
  const float* bl = (const float*)d_in[14];
  const float* wr = (const float*)d_in[15];
  float* out = (float*)d_out;

  // workspace layout (4-byte words; csr kept 8B-aligned)
  float* ws = (float*)d_ws;
  float* M1 = ws;                                   // 8192
  float* c1 = M1 + F_IN * H1;                       // 64
  float* M2 = c1 + H1;                              // 2048
  float* c2 = M2 + H1 * H2;                         // 32
  unsigned* ybf = (unsigned*)(c2 + H2);             // N*32
  unsigned* zbf = ybf + (size_t)N_NODES * 32;       // N*16
  float* p = (float*)(zbf + (size_t)N_NODES * 16);  // N
  float* r = p + N_NODES;                           // N
  int2* csr = (int2*)(r + N_NODES);                 // E int2
  int* counts = (int*)(csr + N_EDGES);              // N
  int* cursor = counts + N_NODES;                   // N
  int* bsums = cursor + N_NODES;                    // NBLK
  int* row_ptr = bsums + NBLK;                      // N+1

  hipMemsetAsync(counts, 0, sizeof(int) * (size_t)N_NODES, stream);

  prep_and_count<<<PREP_BLOCKS + CNT_BLOCKS, 256, 0, stream>>>(
      w1a, b1a, w1b, b1b, w2a, b2a, w2b, b2b, M1, c1, M2, c2, ei, counts);

  block_sums<<<NBLK, 256, 0, stream>>>(counts, bsums);
  emit_rowptr<<<NBLK, 256, 0, stream>>>(counts, bsums, row_ptr, cursor);

  gemm1_fill<<<GEMM1_BLOCKS + FILL_BLOCKS, 256, 0, stream>>>(
      x, M1, ybf, ei, ea, cursor, csr);

  gin2<<<(N_NODES + 63) / 64, 256, 0, stream>>>(ybf, row_ptr, csr, M2, c1,
                                                eps1, zbf);

  gin3<<<(N_NODES * 16 + 255) / 256, 256, 0, stream>>>(zbf, row_ptr, csr, c2,
                                                       eps2, wl, wr, p, r);

  sage_out<<<(N_NODES * 16 + 255) / 256, 256, 0, stream>>>(row_ptr, csr, p, r,
                                                           bl, out);
}

// Round 11
// 222.978 us; speedup vs baseline: 1.4549x; 1.4549x over previous
//
#include <hip/hip_runtime.h>

#define N_NODES 50000
#define N_EDGES 600000
#define F_IN 128
#define H1 64
#define H2 32
#define NBLK ((N_NODES + 255) / 256)        // 196 scan blocks
#define PREP_BLOCKS 41                      // 10336 weight elems / 256
#define CNT_BLOCKS ((N_EDGES / 4 + 255) / 256)   // 586
#define GEMM1_BLOCKS ((N_NODES + 63) / 64)  // 782
#define FILL_BLOCKS ((N_EDGES / 4 + 255) / 256)  // 586

// ---- bf16 pack/unpack helpers (round-to-nearest-even) ---------------------
__device__ inline unsigned bf_round(float x) {
  unsigned u = __float_as_uint(x);
  u += 0x7FFFu + ((u >> 16) & 1u);
  return u >> 16;
}
__device__ inline unsigned pack_bf2(float a, float b) {
  return (bf_round(b) << 16) | bf_round(a);
}
__device__ inline float2 unpack_bf2(unsigned u) {
  return make_float2(__uint_as_float(u << 16), __uint_as_float(u & 0xFFFF0000u));
}

// ---------------------------------------------------------------------------
// Kernel A: fold GIN MLP weights (blocks 0..40)  +  count edges (rest).
// ---------------------------------------------------------------------------
__global__ __launch_bounds__(256) void prep_and_count(
    const float* __restrict__ w1a, const float* __restrict__ b1a,
    const float* __restrict__ w1b, const float* __restrict__ b1b,
    const float* __restrict__ w2a, const float* __restrict__ b2a,
    const float* __restrict__ w2b, const float* __restrict__ b2b,
    float* __restrict__ M1, float* __restrict__ c1,
    float* __restrict__ M2, float* __restrict__ c2,
    const int* __restrict__ ei, int* __restrict__ counts) {
  if (blockIdx.x >= PREP_BLOCKS) {
    int t = (blockIdx.x - PREP_BLOCKS) * 256 + threadIdx.x;
    if (t < N_EDGES / 4) {
      int4 d4 = *reinterpret_cast<const int4*>(&ei[N_EDGES + t * 4]);
      atomicAdd(&counts[d4.x], 1);
      atomicAdd(&counts[d4.y], 1);
      atomicAdd(&counts[d4.z], 1);
      atomicAdd(&counts[d4.w], 1);
    }
    return;
  }
  int i = blockIdx.x * 256 + threadIdx.x;
  if (i < F_IN * H1) {
    int f = i >> 6, h = i & 63;
    float s = 0.f;
    for (int m = 0; m < H1; ++m) s += w1a[m * F_IN + f] * w1b[h * H1 + m];
    M1[i] = s;
    return;
  }
  i -= F_IN * H1;
  if (i < H1) {
    float s = b1b[i];
    for (int m = 0; m < H1; ++m) s += b1a[m] * w1b[i * H1 + m];
    c1[i] = s;
    return;
  }
  i -= H1;
  if (i < H1 * H2) {
    int h = i >> 5, o = i & 31;
    float s = 0.f;
    for (int m = 0; m < H2; ++m) s += w2a[m * H1 + h] * w2b[o * H2 + m];
    M2[i] = s;
    return;
  }
  i -= H1 * H2;
  if (i < H2) {
    float s = b2b[i];
    for (int m = 0; m < H2; ++m) s += b2a[m] * w2b[i * H2 + m];
    c2[i] = s;
  }
}

// -------------------- CSR scan phases --------------------------------------
__global__ __launch_bounds__(256) void block_sums(const int* __restrict__ counts,
                                                  int* __restrict__ bsums) {
  __shared__ int s[256];
  int t = threadIdx.x;
  int i = blockIdx.x * 256 + t;
  s[t] = (i < N_NODES) ? counts[i] : 0;
  __syncthreads();
  for (int off = 128; off > 0; off >>= 1) {
    if (t < off) s[t] += s[t + off];
    __syncthreads();
  }
  if (t == 0) bsums[blockIdx.x] = s[0];
}

// emit_rowptr with the bsums scan folded in: every block redundantly scans
// the NBLK (=196) block sums in LDS (trivial), then does its local scan.
__global__ __launch_bounds__(256) void emit_rowptr(const int* __restrict__ counts,
                                                   const int* __restrict__ bsums,
                                                   int* __restrict__ row_ptr,
                                                   int* __restrict__ cursor) {
  __shared__ int sb[256];
  __shared__ int s[256];
  int t = threadIdx.x;
  int bv = (t < NBLK) ? bsums[t] : 0;
  sb[t] = bv;
  __syncthreads();
  for (int off = 1; off < 256; off <<= 1) {
    int u = (t >= off) ? sb[t - off] : 0;
    __syncthreads();
    sb[t] += u;
    __syncthreads();
  }
  if (blockIdx.x == 0 && t == NBLK - 1) row_ptr[N_NODES] = sb[t];
  int boff = (blockIdx.x == 0) ? 0 : sb[blockIdx.x - 1];
  int i = blockIdx.x * 256 + t;
  int v = (i < N_NODES) ? counts[i] : 0;
  s[t] = v;
  __syncthreads();
  for (int off = 1; off < 256; off <<= 1) {
    int u = (t >= off) ? s[t - off] : 0;
    __syncthreads();
    s[t] += u;
    __syncthreads();
  }
  if (i < N_NODES) {
    int ex = boff + s[t] - v;
    row_ptr[i] = ex;
    cursor[i] = ex;
  }
}

// ---------------------------------------------------------------------------
// Merged dispatch: blocks [0, GEMM1_BLOCKS) -> y = x@M1 -> bf16,
//                  blocks [GEMM1_BLOCKS, +FILL_BLOCKS) -> packed CSR fill.
// ---------------------------------------------------------------------------
__global__ __launch_bounds__(256) void gemm1_fill(
    const float* __restrict__ x, const float* __restrict__ M1,
    unsigned* __restrict__ ybf, const int* __restrict__ ei,
    const float* __restrict__ ea, int* __restrict__ cursor,
    int2* __restrict__ csr) {
  __shared__ float sW[F_IN * H1];   // 32 KiB, [k][col]
  __shared__ float sX[32][H1];      // 8 KiB,  [k][row]
  if (blockIdx.x >= GEMM1_BLOCKS) {
    int t = (blockIdx.x - GEMM1_BLOCKS) * 256 + threadIdx.x;
    if (t < N_EDGES / 4) {
      int4 s4 = *reinterpret_cast<const int4*>(&ei[4 * t]);
      int4 d4 = *reinterpret_cast<const int4*>(&ei[N_EDGES + 4 * t]);
      float4 w4 = *reinterpret_cast<const float4*>(&ea[4 * t]);
      int p0 = atomicAdd(&cursor[d4.x], 1);
      csr[p0] = make_int2(s4.x, __float_as_int(w4.x));
      int p1 = atomicAdd(&cursor[d4.y], 1);
      csr[p1] = make_int2(s4.y, __float_as_int(w4.y));
      int p2 = atomicAdd(&cursor[d4.z], 1);
      csr[p2] = make_int2(s4.z, __float_as_int(w4.z));
      int p3 = atomicAdd(&cursor[d4.w], 1);
      csr[p3] = make_int2(s4.w, __float_as_int(w4.w));
    }
    return;
  }
  int tid = threadIdx.x;
  for (int i = tid; i < F_IN * H1; i += 256) sW[i] = M1[i];

  int row0 = blockIdx.x * 64;
  int tr = tid >> 4;   // 0..15
  int tc = tid & 15;   // 0..15
  int lrow = tid & 63;
  int kgrp = tid >> 6; // 0..3
  const float* xrow = x + (long long)(row0 + lrow) * F_IN;
  bool rvalid = (row0 + lrow) < N_NODES;

  float acc[4][4] = {{0.f}};

  for (int kc = 0; kc < 4; ++kc) {
    float4 v0 = make_float4(0.f, 0.f, 0.f, 0.f);
    float4 v1 = make_float4(0.f, 0.f, 0.f, 0.f);
    if (rvalid) {
      v0 = *reinterpret_cast<const float4*>(xrow + kc * 32 + kgrp * 8);
      v1 = *reinterpret_cast<const float4*>(xrow + kc * 32 + kgrp * 8 + 4);
    }
    __syncthreads();
    sX[kgrp * 8 + 0][lrow] = v0.x;
    sX[kgrp * 8 + 1][lrow] = v0.y;
    sX[kgrp * 8 + 2][lrow] = v0.z;
    sX[kgrp * 8 + 3][lrow] = v0.w;
    sX[kgrp * 8 + 4][lrow] = v1.x;
    sX[kgrp * 8 + 5][lrow] = v1.y;
    sX[kgrp * 8 + 6][lrow] = v1.z;
    sX[kgrp * 8 + 7][lrow] = v1.w;
    __syncthreads();
#pragma unroll
    for (int k = 0; k < 32; ++k) {
      float4 a = *reinterpret_cast<const float4*>(&sX[k][tr * 4]);
      float4 b = *reinterpret_cast<const float4*>(&sW[(kc * 32 + k) * H1 + tc * 4]);
      acc[0][0] += a.x * b.x; acc[0][1] += a.x * b.y;
      acc[0][2] += a.x * b.z; acc[0][3] += a.x * b.w;
      acc[1][0] += a.y * b.x; acc[1][1] += a.y * b.y;
      acc[1][2] += a.y * b.z; acc[1][3] += a.y * b.w;
      acc[2][0] += a.z * b.x; acc[2][1] += a.z * b.y;
      acc[2][2] += a.z * b.z; acc[2][3] += a.z * b.w;
      acc[3][0] += a.w * b.x; acc[3][1] += a.w * b.y;
      acc[3][2] += a.w * b.z; acc[3][3] += a.w * b.w;
    }
  }
#pragma unroll
  for (int i = 0; i < 4; ++i) {
    int row = row0 + tr * 4 + i;
    if (row < N_NODES) {
      uint2 o;
      o.x = pack_bf2(acc[i][0], acc[i][1]);
      o.y = pack_bf2(acc[i][2], acc[i][3]);
      *reinterpret_cast<uint2*>(&ybf[(unsigned)row * 32 + tc * 2]) = o;
    }
  }
}

// ---- agg_h: h = relu((1+e1)*y_self + sum y_nb + c1), fp32 out -------------
// One wave (64 lanes) per node; the two 32-lane halves split the edge list
// ([start,mid) / [mid,end)), each 4-unrolled -> up to 8 outstanding 128B
// loads per wave; one shfl_xor(32) combines. 4 nodes / 256-thr block.
// KEEP THIS KERNEL GATHER-ONLY: fusing the MLP here inflates VGPR to ~196
// and collapses occupancy (R7, R10 post-mortems) — kernel boundary is the
// register-allocation boundary.
__global__ __launch_bounds__(256) void agg_h(
    const unsigned* __restrict__ ybf, const int* __restrict__ row_ptr,
    const int2* __restrict__ csr, const float* __restrict__ c1,
    const float* __restrict__ eps1p, float* __restrict__ h) {
  int tid = threadIdx.x;
  int node = blockIdx.x * 4 + (tid >> 6);
  if (node >= N_NODES) return;
  int lane = tid & 63;
  int half = lane >> 5;
  int j = lane & 31;
  int start = row_ptr[node], end = row_ptr[node + 1];
  int mid = start + ((end - start + 1) >> 1);
  int b0 = half ? mid : start;
  int b1 = half ? end : mid;
  float a0 = 0.f, a1 = 0.f;
  int e = b0;
  for (; e + 4 <= b1; e += 4) {
    int s0 = csr[e + 0].x;
    int s1 = csr[e + 1].x;
    int s2 = csr[e + 2].x;
    int s3 = csr[e + 3].x;
    float2 u0 = unpack_bf2(ybf[(unsigned)s0 * 32 + j]);
    float2 u1 = unpack_bf2(ybf[(unsigned)s1 * 32 + j]);
    float2 u2 = unpack_bf2(ybf[(unsigned)s2 * 32 + j]);
    float2 u3 = unpack_bf2(ybf[(unsigned)s3 * 32 + j]);
    a0 += (u0.x + u1.x) + (u2.x + u3.x);
    a1 += (u0.y + u1.y) + (u2.y + u3.y);
  }
  float2 t0 = make_float2(0.f, 0.f), t1 = make_float2(0.f, 0.f),
         t2 = make_float2(0.f, 0.f);
  if (e + 0 < b1) t0 = unpack_bf2(ybf[(unsigned)csr[e + 0].x * 32 + j]);
  if (e + 1 < b1) t1 = unpack_bf2(ybf[(unsigned)csr[e + 1].x * 32 + j]);
  if (e + 2 < b1) t2 = unpack_bf2(ybf[(unsigned)csr[e + 2].x * 32 + j]);
  a0 += (t0.x + t1.x) + t2.x;
  a1 += (t0.y + t1.y) + t2.y;
  a0 += __shfl_xor(a0, 32);
  a1 += __shfl_xor(a1, 32);
  if (half == 0) {
    float eps1 = 1.0f + *eps1p;
    float2 self = unpack_bf2(ybf[(unsigned)node * 32 + j]);
    float2 c = *reinterpret_cast<const float2*>(&c1[2 * j]);
    float2 hv;
    hv.x = fmaxf(eps1 * self.x + a0 + c.x, 0.f);
    hv.y = fmaxf(eps1 * self.y + a1 + c.y, 0.f);
    *reinterpret_cast<float2*>(&h[(unsigned)node * H1 + 2 * j]) = hv;
  }
}

// -------------------- z = h @ M2 -> packed bf16  (N x 64 -> N x 32) --------
// Register-tiled 64 rows x 32 cols, 4x2 acc/thread.
__global__ __launch_bounds__(256) void gemm2(const float* __restrict__ h,
                                             const float* __restrict__ M2,
                                             unsigned* __restrict__ zbf) {
  __shared__ float sW[H1 * H2];   // 8 KiB, [k][o]
  __shared__ float sX[H1][64];    // 16 KiB, [k][row]
  int tid = threadIdx.x;
  for (int i = tid; i < H1 * H2; i += 256) sW[i] = M2[i];

  int row0 = blockIdx.x * 64;
  int lrow = tid & 63;
  int kg = tid >> 6;  // 0..3, 16 k's each
  bool rv = (row0 + lrow) < N_NODES;
  float4 v[4] = {};
  if (rv) {
    const float* hr = h + (long long)(row0 + lrow) * H1 + kg * 16;
#pragma unroll
    for (int q = 0; q < 4; ++q) v[q] = *reinterpret_cast<const float4*>(hr + q * 4);
  }
#pragma unroll
  for (int q = 0; q < 4; ++q) {
    sX[kg * 16 + q * 4 + 0][lrow] = v[q].x;
    sX[kg * 16 + q * 4 + 1][lrow] = v[q].y;
    sX[kg * 16 + q * 4 + 2][lrow] = v[q].z;
    sX[kg * 16 + q * 4 + 3][lrow] = v[q].w;
  }
  __syncthreads();
  int tr = tid >> 4;  // 0..15, 4 rows each
  int tc = tid & 15;  // 0..15, 2 cols each
  float acc[4][2] = {{0.f}};
#pragma unroll
  for (int k = 0; k < H1; ++k) {
    float4 a = *reinterpret_cast<const float4*>(&sX[k][tr * 4]);
    float2 b = *reinterpret_cast<const float2*>(&sW[k * H2 + tc * 2]);
    acc[0][0] += a.x * b.x; acc[0][1] += a.x * b.y;
    acc[1][0] += a.y * b.x; acc[1][1] += a.y * b.y;
    acc[2][0] += a.z * b.x; acc[2][1] += a.z * b.y;
    acc[3][0] += a.w * b.x; acc[3][1] += a.w * b.y;
  }
#pragma unroll
  for (int i = 0; i < 4; ++i) {
    int row = row0 + tr * 4 + i;
    if (row < N_NODES)
      zbf[(unsigned)row * 16 + tc] = pack_bf2(acc[i][0], acc[i][1]);
  }
}

// ---- gin3: h2 = relu((1+e2)*z_self + sum z_nb + c2); p=h2.wl, r=h2.wr -----
// 16 lanes per node (lane j = features 2j,2j+1); 16 nodes / block.
__global__ __launch_bounds__(256) void gin3(
    const unsigned* __restrict__ zbf, const int* __restrict__ row_ptr,
    const int2* __restrict__ csr, const float* __restrict__ c2,
    const float* __restrict__ eps2p, const float* __restrict__ wl,
    const float* __restrict__ wr, float* __restrict__ p,
    float* __restrict__ r) {
  int tid = blockIdx.x * 256 + threadIdx.x;
  int node = tid >> 4;
  if (node >= N_NODES) return;
  int j = tid & 15;
  int start = row_ptr[node], end = row_ptr[node + 1];
  float a0 = 0.f, a1 = 0.f;
  int e = start;
  for (; e + 8 <= end; e += 8) {
    int s0 = csr[e + 0].x; int s1 = csr[e + 1].x;
    int s2 = csr[e + 2].x; int s3 = csr[e + 3].x;
    int s4 = csr[e + 4].x; int s5 = csr[e + 5].x;
    int s6 = csr[e + 6].x; int s7 = csr[e + 7].x;
    float2 u0 = unpack_bf2(zbf[(unsigned)s0 * 16 + j]);
    float2 u1 = unpack_bf2(zbf[(unsigned)s1 * 16 + j]);
    float2 u2 = unpack_bf2(zbf[(unsigned)s2 * 16 + j]);
    float2 u3 = unpack_bf2(zbf[(unsigned)s3 * 16 + j]);
    float2 u4 = unpack_bf2(zbf[(unsigned)s4 * 16 + j]);
    float2 u5 = unpack_bf2(zbf[(unsigned)s5 * 16 + j]);
    float2 u6 = unpack_bf2(zbf[(unsigned)s6 * 16 + j]);
    float2 u7 = unpack_bf2(zbf[(unsigned)s7 * 16 + j]);
    a0 += ((u0.x + u1.x) + (u2.x + u3.x)) + ((u4.x + u5.x) + (u6.x + u7.x));
    a1 += ((u0.y + u1.y) + (u2.y + u3.y)) + ((u4.y + u5.y) + (u6.y + u7.y));
  }
  for (; e + 4 <= end; e += 4) {
    int s0 = csr[e + 0].x; int s1 = csr[e + 1].x;
    int s2 = csr[e + 2].x; int s3 = csr[e + 3].x;
    float2 u0 = unpack_bf2(zbf[(unsigned)s0 * 16 + j]);
    float2 u1 = unpack_bf2(zbf[(unsigned)s1 * 16 + j]);
    float2 u2 = unpack_bf2(zbf[(unsigned)s2 * 16 + j]);
    float2 u3 = unpack_bf2(zbf[(unsigned)s3 * 16 + j]);
    a0 += (u0.x + u1.x) + (u2.x + u3.x);
    a1 += (u0.y + u1.y) + (u2.y + u3.y);
  }
  float2 t0 = make_float2(0.f, 0.f), t1 = make_float2(0.f, 0.f),
         t2 = make_float2(0.f, 0.f);
  if (e + 0 < end) t0 = unpack_bf2(zbf[(unsigned)csr[e + 0].x * 16 + j]);
  if (e + 1 < end) t1 = unpack_bf2(zbf[(unsigned)csr[e + 1].x * 16 + j]);
  if (e + 2 < end) t2 = unpack_bf2(zbf[(unsigned)csr[e + 2].x * 16 + j]);
  a0 += (t0.x + t1.x) + t2.x;
  a1 += (t0.y + t1.y) + t2.y;
  float eps2 = 1.0f + *eps2p;
  float2 self = unpack_bf2(zbf[(unsigned)node * 16 + j]);
  float2 c = *reinterpret_cast<const float2*>(&c2[2 * j]);
  float h0 = fmaxf(eps2 * self.x + a0 + c.x, 0.f);
  float h1 = fmaxf(eps2 * self.y + a1 + c.y, 0.f);
  float2 l = *reinterpret_cast<const float2*>(&wl[2 * j]);
  float2 w = *reinterpret_cast<const float2*>(&wr[2 * j]);
  float pd = h0 * l.x + h1 * l.y;
  float rd = h0 * w.x + h1 * w.y;
#pragma unroll
  for (int m = 8; m >= 1; m >>= 1) {
    pd += __shfl_xor(pd, m, 16);
    rd += __shfl_xor(rd, m, 16);
  }
  if (j == 0) {
    p[node] = pd;
    r[node] = rd;
  }
}

// ---- SAGE: mean of ew*p[src] over in-edges + root path, relu --------------
__global__ __launch_bounds__(256) void sage_out(
    const int* __restrict__ row_ptr, const int2* __restrict__ csr,
    const float* __restrict__ p, const float* __restrict__ r,
    const float* __restrict__ blp, float* __restrict__ out) {
  int idx = blockIdx.x * 256 + threadIdx.x;
  int node = idx >> 4;
  if (node >= N_NODES) return;
  int l = idx & 15;
  int start = row_ptr[node], end = row_ptr[node + 1];
  float acc = 0.f;
  for (int e = start + l; e < end; e += 16) {
    int2 c = csr[e];
    acc += __int_as_float(c.y) * p[c.x];
  }
#pragma unroll
  for (int m = 8; m >= 1; m >>= 1) acc += __shfl_xor(acc, m, 16);
  if (l == 0) {
    float mean = acc / fmaxf((float)(end - start), 1.0f);
    out[node] = fmaxf(mean + blp[0] + r[node], 0.f);
  }
}

extern "C" void kernel_launch(void* const* d_in, const int* in_sizes, int n_in,
                              void* d_out, int out_size, void* d_ws,
                              size_t ws_size, hipStream_t stream) {
  const float* x = (const float*)d_in[0];
  const int* ei = (const int*)d_in[1];
  const float* ea = (const float*)d_in[2];
  const float* w1a = (const float*)d_in[3];
  const float* b1a = (const float*)d_in[4];
  const float* w1b = (const float*)d_in[5];
  const float* b1b = (const float*)d_in[6];
  const float* eps1 = (const float*)d_in[7];
  const float* w2a = (const float*)d_in[8];
  const float* b2a = (const float*)d_in[9];
  const float* w2b = (const float*)d_in[10];
  const float* b2b = (const float*)d_in[11];
  const float* eps2 = (const float*)d_in[12];
  const float* wl = (const float*)d_in[13];
  const float* bl = (const float*)d_in[14];
  const float* wr = (const float*)d_in[15];
  float* out = (float*)d_out;

  // workspace layout (4-byte words; csr kept 8B-aligned)
  float* ws = (float*)d_ws;
  float* M1 = ws;                                   // 8192
  float* c1 = M1 + F_IN * H1;                       // 64
  float* M2 = c1 + H1;                              // 2048
  float* c2 = M2 + H1 * H2;                         // 32
  unsigned* ybf = (unsigned*)(c2 + H2);             // N*32
  float* h = (float*)(ybf + (size_t)N_NODES * 32);  // N*64
  unsigned* zbf = (unsigned*)(h + (size_t)N_NODES * H1);  // N*16
  float* p = (float*)(zbf + (size_t)N_NODES * 16);  // N
  float* r = p + N_NODES;                           // N
  int2* csr = (int2*)(r + N_NODES);                 // E int2
  int* counts = (int*)(csr + N_EDGES);              // N
  int* cursor = counts + N_NODES;                   // N
  int* bsums = cursor + N_NODES;                    // NBLK
  int* row_ptr = bsums + NBLK;                      // N+1

  hipMemsetAsync(counts, 0, sizeof(int) * (size_t)N_NODES, stream);

  prep_and_count<<<PREP_BLOCKS + CNT_BLOCKS, 256, 0, stream>>>(
      w1a, b1a, w1b, b1b, w2a, b2a, w2b, b2b, M1, c1, M2, c2, ei, counts);

  block_sums<<<NBLK, 256, 0, stream>>>(counts, bsums);
  emit_rowptr<<<NBLK, 256, 0, stream>>>(counts, bsums, row_ptr, cursor);

  gemm1_fill<<<GEMM1_BLOCKS + FILL_BLOCKS, 256, 0, stream>>>(
      x, M1, ybf, ei, ea, cursor, csr);

  agg_h<<<(N_NODES + 3) / 4, 256, 0, stream>>>(ybf, row_ptr, csr, c1, eps1, h);

  gemm2<<<(N_NODES + 63) / 64, 256, 0, stream>>>(h, M2, zbf);

  gin3<<<(N_NODES * 16 + 255) / 256, 256, 0, stream>>>(zbf, row_ptr, csr, c2,
                                                       eps2, wl, wr, p, r);

  sage_out<<<(N_NODES * 16 + 255) / 256, 256, 0, stream>>>(row_ptr, csr, p, r,
                                                           bl, out);
}